// Round 1
// 848.500 us; speedup vs baseline: 1.1615x; 1.1615x over previous
//
#include <hip/hip_runtime.h>
#include <math.h>

#define B_   64
#define T_   2048
#define HID_ 128
#define G3_  384   // 3*HID
#define IN_  128
#define E_   64

#define TS_  128   // t-tile of gi GEMM block

typedef _Float16 h2f  __attribute__((ext_vector_type(2)));
typedef _Float16 f16x8 __attribute__((ext_vector_type(8)));
typedef float    f32x4 __attribute__((ext_vector_type(4)));

#define L2E  1.4426950408889634f   // log2(e)
#define L2E2 2.8853900817779268f   // 2*log2(e)

#if __has_builtin(__builtin_amdgcn_exp2f)
#define EXP2(x) __builtin_amdgcn_exp2f(x)
#else
#define EXP2(x) __expf((x) * 0.6931471805599453f)
#endif

__device__ __forceinline__ float rcp_(float x)     { return __builtin_amdgcn_rcpf(x); }
__device__ __forceinline__ float sigmoid_(float x) { return rcp_(1.f + __expf(-x)); }
__device__ __forceinline__ float tanh_(float x)    { return 1.f - 2.f * rcp_(1.f + __expf(2.f * x)); }

// pack 8 f32 -> f16x8 via 4x cvt_pkrtz
__device__ __forceinline__ f16x8 pack8_(float4 a, float4 b) {
    uint4 u;
    u.x = __builtin_bit_cast(unsigned, __builtin_amdgcn_cvt_pkrtz(a.x, a.y));
    u.y = __builtin_bit_cast(unsigned, __builtin_amdgcn_cvt_pkrtz(a.z, a.w));
    u.z = __builtin_bit_cast(unsigned, __builtin_amdgcn_cvt_pkrtz(b.x, b.y));
    u.w = __builtin_bit_cast(unsigned, __builtin_amdgcn_cvt_pkrtz(b.z, b.w));
    return __builtin_bit_cast(f16x8, u);
}

// ---------------------------------------------------------------------------
// gi GEMM, f16 MFMA (unchanged, verified).
// ---------------------------------------------------------------------------
__global__ __launch_bounds__(256, 1)
void gi_gemm(const float* __restrict__ x, const float* __restrict__ w_ih,
             const float* __restrict__ b_ih, const float* __restrict__ b_hh,
             float* __restrict__ gi, int t0)
{
    const int tid = threadIdx.x;
    const int w   = tid >> 6;
    const int l   = tid & 63;
    const int ln  = l & 15;
    const int kq  = l >> 4;
    const int tt  = blockIdx.x;
    const int b   = blockIdx.y;
    const int tl_base = tt * TS_ + w * 32;

    float bias_r[24];
    #pragma unroll
    for (int nt = 0; nt < 24; nt++) {
        const int col = nt * 16 + ln;
        bias_r[nt] = b_ih[col] + (col < 256 ? b_hh[col] : 0.f);
    }

    f32x4 acc[2][24];
    #pragma unroll
    for (int mt = 0; mt < 2; mt++)
        #pragma unroll
        for (int nt = 0; nt < 24; nt++)
            acc[mt][nt] = (f32x4){0.f, 0.f, 0.f, 0.f};

    const float* xb = x + ((size_t)b * T_ + (size_t)(t0 + tl_base)) * IN_;

    #pragma unroll
    for (int kc = 0; kc < 4; kc++) {
        const int ko = kc * 32 + kq * 8;
        f16x8 afr[2];
        #pragma unroll
        for (int mt = 0; mt < 2; mt++) {
            const float* xr = xb + (size_t)(mt * 16 + ln) * IN_ + ko;
            float4 p0 = *reinterpret_cast<const float4*>(xr);
            float4 p1 = *reinterpret_cast<const float4*>(xr + 4);
            afr[mt] = pack8_(p0, p1);
        }
        #pragma unroll
        for (int nt = 0; nt < 24; nt++) {
            const float* wr = w_ih + (size_t)(nt * 16 + ln) * IN_ + ko;
            float4 q0 = *reinterpret_cast<const float4*>(wr);
            float4 q1 = *reinterpret_cast<const float4*>(wr + 4);
            const f16x8 bfr = pack8_(q0, q1);
            acc[0][nt] = __builtin_amdgcn_mfma_f32_16x16x32_f16(afr[0], bfr, acc[0][nt], 0, 0, 0);
            acc[1][nt] = __builtin_amdgcn_mfma_f32_16x16x32_f16(afr[1], bfr, acc[1][nt], 0, 0, 0);
        }
    }

    #pragma unroll
    for (int mt = 0; mt < 2; mt++) {
        #pragma unroll
        for (int r = 0; r < 4; r++) {
            const size_t trow = (size_t)(tl_base + mt * 16 + kq * 4 + r);
            float* go = gi + trow * (B_ * G3_) + (size_t)b * G3_ + ln;
            #pragma unroll
            for (int nt = 0; nt < 24; nt++)
                go[nt * 16] = acc[mt][nt][r] + bias_r[nt];
        }
    }
}

// ---------------------------------------------------------------------------
// GRU recurrence, 8 waves/block (2 waves per SIMD). Each wave owns ONE
// h-column family: wave w -> h-col cg = 16*(w&3) + ln + 64*(w>>2). Per step
// each wave does 3 gate tiles x 4 k-chunks = 12 MFMAs (replicated-A broadcast
// read of packed-f16 h from LDS). Per-SIMD matrix occupancy is unchanged
// (2 x 12 x ~16 cyc = ~386) but each SIMD now has a partner wave whose MFMA
// issue covers the other wave's serial tail (ds_read latency, exp/rcp chain,
// barrier), and per-wave serial work is halved (6 transcendentals, 3 gi
// loads). w_hh fragments for r/z are pre-scaled by log2(e), n by 2*log2(e),
// so the gate args feed v_exp_f32 (exp2) via a single FMA -- no mul in the
// dependent chain. gi prefetched 2 steps ahead (ring-4), unchanged.
// C/D layout (session-verified): col=ln -> gate row 128*g + cg; A rows are
// replicated copies -> use reg[0].
// ---------------------------------------------------------------------------
#define REC_STEP(CUR, LD, TLOAD, PB)                                           \
  {                                                                            \
    const float* gp_ = gib + (size_t)(TLOAD) * S;                              \
    LD[0] = gp_[cg]; LD[1] = gp_[cg + 128]; LD[2] = gp_[cg + 256];             \
    const char* hb_ = (const char*)(&h2_sh[PB][0]) + kq * 16;                  \
    f16x8 af_[4];                                                              \
    af_[0] = __builtin_bit_cast(f16x8, *(const uint4*)(hb_));                  \
    af_[1] = __builtin_bit_cast(f16x8, *(const uint4*)(hb_ + 64));             \
    af_[2] = __builtin_bit_cast(f16x8, *(const uint4*)(hb_ + 128));            \
    af_[3] = __builtin_bit_cast(f16x8, *(const uint4*)(hb_ + 192));            \
    f32x4 ac_[3];                                                              \
    _Pragma("unroll")                                                          \
    for (int g = 0; g < 3; g++) ac_[g] = (f32x4){0.f, 0.f, 0.f, 0.f};          \
    _Pragma("unroll")                                                          \
    for (int kc = 0; kc < 4; kc++) {                                           \
      _Pragma("unroll")                                                        \
      for (int g = 0; g < 3; g++)                                              \
        ac_[g] = __builtin_amdgcn_mfma_f32_16x16x32_f16(af_[kc], wf[g][kc],    \
                                                        ac_[g], 0, 0, 0);      \
    }                                                                          \
    const float q_  = CUR[2] * L2E2;                                           \
    const float yr_ = fmaf(CUR[0], L2E, ac_[0][0]);                            \
    const float r_  = rcp_(1.f + EXP2(-yr_));                                  \
    const float yz_ = fmaf(CUR[1], L2E, ac_[1][0]);                            \
    const float z_  = rcp_(1.f + EXP2(-yz_));                                  \
    const float yn_ = fmaf(r_, ac_[2][0] + bh, q_);                            \
    const float u_  = rcp_(1.f + EXP2(yn_));                                   \
    const float n_  = fmaf(-2.f, u_, 1.f);                                     \
    hj = n_ + z_ * (hj - n_);                                                  \
    hs += hj;                                                                  \
    if (kq == 0) h2_sh[(PB) ^ 1][cg] = (_Float16)hj;                           \
    __syncthreads();                                                           \
  }

__global__ __launch_bounds__(512, 2)
void rec_kernel(const float* __restrict__ gi, const float* __restrict__ w_hh,
                const float* __restrict__ b_hh,
                const float* __restrict__ w_proj, const float* __restrict__ b_proj,
                float* __restrict__ out, float* __restrict__ state,
                int t0, int t1)
{
    const int tid  = threadIdx.x;
    const int b    = blockIdx.x;
    const int w    = tid >> 6;     // wave 0..7
    const int lane = tid & 63;
    const int ln   = lane & 15;
    const int kq   = lane >> 4;
    const int wh   = w & 3;        // col-tile within family
    const int f    = w >> 2;       // family 0 (cols 0..63) / 1 (cols 64..127)
    const int cg   = 16 * wh + ln + 64 * f;   // this lane's h column
    const int nT   = t1 - t0;      // multiple of 128 -> multiple of 4

    __shared__ _Float16 h2_sh[2][HID_];   // h as f16, double-buffered
    __shared__ float pooled[HID_];

    // B-frags: wf[g][kc] = packed w_hh[128*g + cg][kc*32+kq*8 .. +8),
    // pre-scaled: r,z by log2(e); n by 2*log2(e) (exp2-direct gates).
    f16x8 wf[3][4];
    #pragma unroll
    for (int g = 0; g < 3; g++) {
        const float s = (g == 2) ? L2E2 : L2E;
        const float* wr = w_hh + (size_t)(128 * g + cg) * HID_;
        #pragma unroll
        for (int kc = 0; kc < 4; kc++) {
            const float* p = wr + kc * 32 + kq * 8;
            float4 q0 = *reinterpret_cast<const float4*>(p);
            float4 q1 = *reinterpret_cast<const float4*>(p + 4);
            q0.x *= s; q0.y *= s; q0.z *= s; q0.w *= s;
            q1.x *= s; q1.y *= s; q1.z *= s; q1.w *= s;
            wf[g][kc] = pack8_(q0, q1);
        }
    }
    const float bh = L2E2 * b_hh[256 + cg];   // n-gate hidden bias, pre-scaled

    float hj, hs;
    if (t0 == 0) { hj = hs = 0.f; }
    else {
        hj = state[b * HID_ + cg];
        hs = state[B_ * HID_ + b * HID_ + cg];
    }
    if (kq == 0) h2_sh[0][cg] = (_Float16)hj;
    __syncthreads();

    const float* gib = gi + (size_t)b * G3_;
    const size_t S = (size_t)B_ * G3_;

    // ring-4 gi buffers; prefetch depth 2
    float g0[3], g1[3], g2[3], g3[3];
    {
        const float* p0 = gib;
        const float* p1 = gib + S;
        g0[0] = p0[cg]; g0[1] = p0[cg + 128]; g0[2] = p0[cg + 256];
        g1[0] = p1[cg]; g1[1] = p1[cg + 128]; g1[2] = p1[cg + 256];
    }

    int pb = 0;
    for (int t = 0; t < nT; t += 4) {
        const int nTm1 = nT - 1;
        int t2 = t + 2 < nTm1 ? t + 2 : nTm1;
        int t3 = t + 3 < nTm1 ? t + 3 : nTm1;
        int t4 = t + 4 < nTm1 ? t + 4 : nTm1;
        int t5 = t + 5 < nTm1 ? t + 5 : nTm1;
        REC_STEP(g0, g2, t2, pb); pb ^= 1;
        REC_STEP(g1, g3, t3, pb); pb ^= 1;
        REC_STEP(g2, g0, t4, pb); pb ^= 1;
        REC_STEP(g3, g1, t5, pb); pb ^= 1;
    }

    if (t1 < T_) {
        if (kq == 0) {
            state[b * HID_ + cg]             = hj;
            state[B_ * HID_ + b * HID_ + cg] = hs;
        }
    } else {
        if (kq == 0) pooled[cg] = hs * (1.f / (float)T_);
        __syncthreads();
        if (tid < E_) {
            const float4* wpj = reinterpret_cast<const float4*>(w_proj + (size_t)tid * HID_);
            const float4* pp  = reinterpret_cast<const float4*>(pooled);
            float a0 = 0.f, a1 = 0.f, a2 = 0.f, a3 = 0.f;
            #pragma unroll
            for (int k = 0; k < 32; k++) {
                float4 wv = wpj[k]; float4 pv = pp[k];
                a0 = fmaf(wv.x, pv.x, a0);
                a1 = fmaf(wv.y, pv.y, a1);
                a2 = fmaf(wv.z, pv.z, a2);
                a3 = fmaf(wv.w, pv.w, a3);
            }
            out[b * E_ + tid] = (a0 + a1) + (a2 + a3) + b_proj[tid];
        }
    }
}

extern "C" void kernel_launch(void* const* d_in, const int* in_sizes, int n_in,
                              void* d_out, int out_size, void* d_ws, size_t ws_size,
                              hipStream_t stream)
{
    const float* x      = (const float*)d_in[0];
    const float* w_ih   = (const float*)d_in[1];
    const float* w_hh   = (const float*)d_in[2];
    const float* b_ih   = (const float*)d_in[3];
    const float* b_hh   = (const float*)d_in[4];
    const float* w_proj = (const float*)d_in[5];
    const float* b_proj = (const float*)d_in[6];
    float* out = (float*)d_out;

    // ws layout: [ gi chunk buffer: chunkT * B * 3H * f32 ][ state: h + hsum ]
    const size_t state_bytes = (size_t)2 * B_ * HID_ * sizeof(float);
    const size_t per_t = (size_t)B_ * G3_ * sizeof(float);
    size_t avail = ws_size > state_bytes ? ws_size - state_bytes : 0;
    int chunkT = (int)(avail / per_t);
    if (chunkT > T_) chunkT = T_;
    chunkT &= ~(TS_ - 1);
    if (chunkT < TS_) chunkT = TS_;

    float* gi_buf = (float*)d_ws;
    float* state  = (float*)((char*)d_ws + (size_t)chunkT * per_t);

    for (int t0 = 0; t0 < T_; t0 += chunkT) {
        int t1 = t0 + chunkT; if (t1 > T_) t1 = T_;
        int nT = t1 - t0;
        gi_gemm<<<dim3(nT / TS_, B_), dim3(256), 0, stream>>>(x, w_ih, b_ih, b_hh, gi_buf, t0);
        rec_kernel<<<dim3(B_), dim3(512), 0, stream>>>(gi_buf, w_hh, b_hh, w_proj, b_proj,
                                                       out, state, t0, t1);
    }
}